// Round 1
// baseline (16458.403 us; speedup 1.0000x reference)
//
#include <hip/hip_runtime.h>

#define BM 64
#define BN 64
#define BK 16

// ---------------- GEMM: C[N,DOUT] = A[N,K] @ W[K,DOUT] + bias ----------------
__global__ __launch_bounds__(256) void gemm_bias_kernel(
    const float* __restrict__ A, int lda,
    const float* __restrict__ W,        // [K, DOUT] row-major
    const float* __restrict__ bias,     // [DOUT]
    float* __restrict__ C, int ldc, int col0,
    int N, int K, int DOUT)
{
    __shared__ float As[BK][BM + 4];
    __shared__ float Bs[BK][BN + 4];
    const int tid = threadIdx.x;
    const int tx = tid & 15, ty = tid >> 4;
    const int m0 = blockIdx.x * BM, n0 = blockIdx.y * BN;
    float acc[4][4] = {};
    const int ar = tid >> 2, ak = (tid & 3) << 2;   // A tile: 64 rows x 16 k
    const int br = tid >> 4, bn = (tid & 15) << 2;  // B tile: 16 k x 64 cols

    for (int k0 = 0; k0 < K; k0 += BK) {
        float4 av = make_float4(0.f, 0.f, 0.f, 0.f);
        int grow = m0 + ar, gk = k0 + ak;
        if (grow < N) {
            if (gk + 3 < K) {
                av = *(const float4*)(A + (long long)grow * lda + gk);
            } else {
                float t0 = 0.f, t1 = 0.f, t2 = 0.f, t3 = 0.f;
                if (gk + 0 < K) t0 = A[(long long)grow * lda + gk + 0];
                if (gk + 1 < K) t1 = A[(long long)grow * lda + gk + 1];
                if (gk + 2 < K) t2 = A[(long long)grow * lda + gk + 2];
                if (gk + 3 < K) t3 = A[(long long)grow * lda + gk + 3];
                av = make_float4(t0, t1, t2, t3);
            }
        }
        As[ak + 0][ar] = av.x; As[ak + 1][ar] = av.y;
        As[ak + 2][ar] = av.z; As[ak + 3][ar] = av.w;

        float4 bv = make_float4(0.f, 0.f, 0.f, 0.f);
        int gbk = k0 + br, gn = n0 + bn;
        if (gbk < K && gn + 3 < DOUT)
            bv = *(const float4*)(W + (long long)gbk * DOUT + gn);
        *(float4*)&Bs[br][bn] = bv;
        __syncthreads();

        #pragma unroll
        for (int kk = 0; kk < BK; ++kk) {
            float4 a4 = *(const float4*)&As[kk][ty << 2];
            float4 b4 = *(const float4*)&Bs[kk][tx << 2];
            float a[4] = {a4.x, a4.y, a4.z, a4.w};
            float b[4] = {b4.x, b4.y, b4.z, b4.w};
            #pragma unroll
            for (int i = 0; i < 4; ++i)
                #pragma unroll
                for (int j = 0; j < 4; ++j)
                    acc[i][j] = fmaf(a[i], b[j], acc[i][j]);
        }
        __syncthreads();
    }

    #pragma unroll
    for (int i = 0; i < 4; ++i) {
        int gm = m0 + (ty << 2) + i;
        if (gm >= N) continue;
        #pragma unroll
        for (int j = 0; j < 4; ++j) {
            int gn = n0 + (tx << 2) + j;
            if (gn < DOUT)
                C[(long long)gm * ldc + col0 + gn] = acc[i][j] + bias[gn];
        }
    }
}

// ------------- scatter: out[dst] += Wh[src] * invcnt[dst] (atomic) -----------
__global__ void scatter_kernel(
    const float* __restrict__ Wh, int dlog2,            // Wh: [Nsrc, 2^dlog2]
    const int* __restrict__ src, const int* __restrict__ dst,
    const float* __restrict__ inv,
    float* __restrict__ out, int ldo, int col0, int E)
{
    const int vlog2 = dlog2 - 2;
    long long idx = (long long)blockIdx.x * blockDim.x + threadIdx.x;
    long long total = (long long)E << vlog2;
    if (idx >= total) return;
    int e  = (int)(idx >> vlog2);
    int c4 = (int)((idx & (((long long)1 << vlog2) - 1)) << 2);
    int s = src[e], d = dst[e];
    float4 v = *(const float4*)(Wh + ((long long)s << dlog2) + c4);
    float sc = inv[d];
    float* base = out + (long long)d * ldo + col0 + c4;
    atomicAdd(base + 0, v.x * sc);
    atomicAdd(base + 1, v.y * sc);
    atomicAdd(base + 2, v.z * sc);
    atomicAdd(base + 3, v.w * sc);
}

// --------------------------- small helper kernels ----------------------------
__global__ void zero_region_kernel(float* __restrict__ base, int ld, int wlog2,
                                   long long total)
{
    long long idx = (long long)blockIdx.x * blockDim.x + threadIdx.x;
    if (idx >= total) return;
    long long r = idx >> wlog2;
    int c = (int)(idx & (((long long)1 << wlog2) - 1));
    base[r * ld + c] = 0.f;
}

__global__ void zero_i32_kernel(int* __restrict__ p, int n)
{
    int i = blockIdx.x * blockDim.x + threadIdx.x;
    if (i < n) p[i] = 0;
}

__global__ void count_kernel(const int* __restrict__ dst, int E, int* __restrict__ cnt)
{
    int i = blockIdx.x * blockDim.x + threadIdx.x;
    if (i < E) atomicAdd(&cnt[dst[i]], 1);
}

__global__ void inv_kernel(const int* __restrict__ cnt, float* __restrict__ inv, int n)
{
    int i = blockIdx.x * blockDim.x + threadIdx.x;
    if (i < n) inv[i] = 1.0f / (float)max(cnt[i], 1);
}

__global__ void bcast_kernel(const float* __restrict__ emb, float* __restrict__ Fp,
                             int ld, int N)
{
    int idx = blockIdx.x * blockDim.x + threadIdx.x;
    if (idx >= N * 128) return;
    int r = idx >> 7, c = idx & 127;
    Fp[(long long)r * ld + c] = emb[c];
}

// ----------------------------- decoder + softmax -----------------------------
__global__ void decoder_kernel(const float* __restrict__ H, int ld, int N,
                               const float* __restrict__ Wd,  // [128,2]
                               const float* __restrict__ bd,  // [2]
                               float* __restrict__ logits, float* __restrict__ soft)
{
    int n = blockIdx.x * blockDim.x + threadIdx.x;
    if (n >= N) return;
    const float* h = H + (long long)n * ld;
    float s0 = bd[0], s1 = bd[1];
    #pragma unroll
    for (int k = 0; k < 128; k += 4) {
        float4 hv = *(const float4*)(h + k);
        s0 = fmaf(hv.x, Wd[2 * (k + 0) + 0], s0); s1 = fmaf(hv.x, Wd[2 * (k + 0) + 1], s1);
        s0 = fmaf(hv.y, Wd[2 * (k + 1) + 0], s0); s1 = fmaf(hv.y, Wd[2 * (k + 1) + 1], s1);
        s0 = fmaf(hv.z, Wd[2 * (k + 2) + 0], s0); s1 = fmaf(hv.z, Wd[2 * (k + 2) + 1], s1);
        s0 = fmaf(hv.w, Wd[2 * (k + 3) + 0], s0); s1 = fmaf(hv.w, Wd[2 * (k + 3) + 1], s1);
    }
    logits[2 * n + 0] = s0;
    logits[2 * n + 1] = s1;
    float m = fmaxf(s0, s1);
    float e0 = expf(s0 - m), e1 = expf(s1 - m);
    float invs = 1.f / (e0 + e1);
    soft[2 * n + 0] = e0 * invs;
    soft[2 * n + 1] = e1 * invs;
}

// ================================== host =====================================
extern "C" void kernel_launch(void* const* d_in, const int* in_sizes, int n_in,
                              void* d_out, int out_size, void* d_ws, size_t ws_size,
                              hipStream_t stream)
{
    enum { CFG = 0, AST = 1, PT = 2, FT = 3 };
    const int Nnt[4] = {20000, 100000, 50, 10};
    const int stp[8] = {CFG, AST, AST, CFG, PT, CFG, FT, CFG};
    const int dtp[8] = {CFG, AST, CFG, AST, CFG, PT, CFG, FT};

    const float* cfg_label   = (const float*)d_in[0];
    const float* cfg_content = (const float*)d_in[1];
    const float* ast_label   = (const float*)d_in[2];
    const float* ast_content = (const float*)d_in[3];
    const int* esrc[8]; const int* edst[8]; int E[8];
    for (int i = 0; i < 8; ++i) {
        esrc[i] = (const int*)d_in[4 + 2 * i];
        edst[i] = (const int*)d_in[5 + 2 * i];
        E[i]    = in_sizes[4 + 2 * i];
    }
    const float* W_cfg_lab = (const float*)d_in[20]; const float* b_cfg_lab = (const float*)d_in[21];
    const float* W_cfg_con = (const float*)d_in[22]; const float* b_cfg_con = (const float*)d_in[23];
    const float* W_ast_lab = (const float*)d_in[24]; const float* b_ast_lab = (const float*)d_in[25];
    const float* W_ast_con = (const float*)d_in[26]; const float* b_ast_con = (const float*)d_in[27];
    const float* ptest_emb = (const float*)d_in[28];
    const float* ftest_emb = (const float*)d_in[29];
    const float* Wl[5] = {(const float*)d_in[30], (const float*)d_in[32], (const float*)d_in[34],
                          (const float*)d_in[36], (const float*)d_in[38]};
    const float* bl[5] = {(const float*)d_in[31], (const float*)d_in[33], (const float*)d_in[35],
                          (const float*)d_in[37], (const float*)d_in[39]};
    const float* W_dec = (const float*)d_in[40];
    const float* b_dec = (const float*)d_in[41];

    // -------- workspace carve (~474 MB) --------
    char* ws = (char*)d_ws;
    size_t off = 0;
    auto carve = [&](size_t bytes) -> void* {
        void* p = ws + off;
        off = (off + bytes + 255) & ~(size_t)255;
        return p;
    };
    float* F[4];  float* F2[4];
    F[CFG]  = (float*)carve((size_t)20000  * 512 * 4);
    F[AST]  = (float*)carve((size_t)100000 * 512 * 4);
    F[PT]   = (float*)carve((size_t)50     * 512 * 4);
    F[FT]   = (float*)carve((size_t)10     * 512 * 4);
    F2[CFG] = (float*)carve((size_t)20000  * 256 * 4);
    F2[AST] = (float*)carve((size_t)100000 * 256 * 4);
    F2[PT]  = (float*)carve((size_t)50     * 256 * 4);
    F2[FT]  = (float*)carve((size_t)10     * 256 * 4);
    float* Wh = (float*)carve((size_t)100000 * 256 * 4);
    const int totc = 280080; // sum of dst-node counts over 8 etypes
    int*   cnt_all = (int*)carve((size_t)totc * 4);
    float* inv_all = (float*)carve((size_t)totc * 4);
    int* cnt[8]; float* inv[8];
    { size_t o = 0; for (int i = 0; i < 8; ++i) { cnt[i] = cnt_all + o; inv[i] = inv_all + o; o += Nnt[dtp[i]]; } }

    // -------- per-etype in-degree counts -> reciprocals --------
    zero_i32_kernel<<<(totc + 255) / 256, 256, 0, stream>>>(cnt_all, totc);
    for (int i = 0; i < 8; ++i)
        count_kernel<<<(E[i] + 255) / 256, 256, 0, stream>>>(edst[i], E[i], cnt[i]);
    inv_kernel<<<(totc + 255) / 256, 256, 0, stream>>>(cnt_all, inv_all, totc);

    auto gemm = [&](const float* A, int lda, const float* W, const float* b,
                    float* C, int ldc, int col0, int N, int K, int DOUT) {
        dim3 g((N + BM - 1) / BM, DOUT / BN);
        gemm_bias_kernel<<<g, 256, 0, stream>>>(A, lda, W, b, C, ldc, col0, N, K, DOUT);
    };

    // -------- encoders: h0 into F[:,0:128] (stride 512) --------
    gemm(cfg_label,   80,  W_cfg_lab, b_cfg_lab, F[CFG], 512, 0,  20000,  80,  64);
    gemm(cfg_content, 300, W_cfg_con, b_cfg_con, F[CFG], 512, 64, 20000,  300, 64);
    gemm(ast_label,   80,  W_ast_lab, b_ast_lab, F[AST], 512, 0,  100000, 80,  64);
    gemm(ast_content, 300, W_ast_con, b_ast_con, F[AST], 512, 64, 100000, 300, 64);
    bcast_kernel<<<(50 * 128 + 255) / 256, 256, 0, stream>>>(ptest_emb, F[PT], 512, 50);
    bcast_kernel<<<(10 * 128 + 255) / 256, 256, 0, stream>>>(ftest_emb, F[FT], 512, 10);

    // -------- one hetero-GCN layer --------
    auto run_layer = [&](const float* Wstack, const float* bstack, int din, int dout, int dlog2,
                         float* const* inB, int ldin, float* const* outB, int ldout, int colout) {
        for (int t = 0; t < 4; ++t) {
            long long total = (long long)Nnt[t] * dout;
            zero_region_kernel<<<(unsigned)((total + 255) / 256), 256, 0, stream>>>(
                outB[t] + colout, ldout, dlog2, total);
        }
        for (int i = 0; i < 8; ++i) {
            int s = stp[i], d = dtp[i];
            gemm(inB[s], ldin, Wstack + (size_t)i * din * dout, bstack + (size_t)i * dout,
                 Wh, dout, 0, Nnt[s], din, dout);
            long long total = ((long long)E[i] * dout) >> 2;
            scatter_kernel<<<(unsigned)((total + 255) / 256), 256, 0, stream>>>(
                Wh, dlog2, esrc[i], edst[i], inv[i], outB[d], ldout, colout, E[i]);
        }
    };

    // L1: F[:,0:128] -> F2[:,0:128]
    run_layer(Wl[0], bl[0], 128, 128, 7, F,  512, F2, 256, 0);
    // L2: F2[:,0:128] -> F2[:,128:256]  (concat -> F2[:,0:256])
    run_layer(Wl[1], bl[1], 128, 128, 7, F2, 256, F2, 256, 128);
    // L3: F2[:,0:256] -> F[:,0:256]
    run_layer(Wl[2], bl[2], 256, 256, 8, F2, 256, F,  512, 0);
    // L4: F[:,0:256] -> F[:,256:512]   (concat -> F[:,0:512])
    run_layer(Wl[3], bl[3], 256, 256, 8, F,  512, F,  512, 256);
    // L5: F[:,0:512] -> F2[:,0:128]
    run_layer(Wl[4], bl[4], 512, 128, 7, F,  512, F2, 256, 0);

    // -------- decoder + softmax --------
    float* out = (float*)d_out;
    decoder_kernel<<<(20000 + 255) / 256, 256, 0, stream>>>(
        F2[CFG], 256, 20000, W_dec, b_dec, out + 0, out + 40000);
    decoder_kernel<<<(100000 + 255) / 256, 256, 0, stream>>>(
        F2[AST], 256, 100000, W_dec, b_dec, out + 80000, out + 280000);
}

// Round 2
// 7036.842 us; speedup vs baseline: 2.3389x; 2.3389x over previous
//
#include <hip/hip_runtime.h>

// ============================ 64-wide GEMM (encoders) ========================
#define BM 64
#define BN 64
#define BK 16

__global__ __launch_bounds__(256) void gemm_bias_kernel(
    const float* __restrict__ A, int lda,
    const float* __restrict__ W,        // [K, DOUT] row-major
    const float* __restrict__ bias,     // [DOUT]
    float* __restrict__ C, int ldc, int col0,
    int N, int K, int DOUT)
{
    __shared__ float As[BK][BM + 4];
    __shared__ float Bs[BK][BN + 4];
    const int tid = threadIdx.x;
    const int tx = tid & 15, ty = tid >> 4;
    const int m0 = blockIdx.x * BM, n0 = blockIdx.y * BN;
    float acc[4][4] = {};
    const int ar = tid >> 2, ak = (tid & 3) << 2;   // A tile: 64 rows x 16 k
    const int br = tid >> 4, bn = (tid & 15) << 2;  // B tile: 16 k x 64 cols

    for (int k0 = 0; k0 < K; k0 += BK) {
        float4 av = make_float4(0.f, 0.f, 0.f, 0.f);
        int grow = m0 + ar, gk = k0 + ak;
        if (grow < N) {
            if (gk + 3 < K) {
                av = *(const float4*)(A + (long long)grow * lda + gk);
            } else {
                float t0 = 0.f, t1 = 0.f, t2 = 0.f, t3 = 0.f;
                if (gk + 0 < K) t0 = A[(long long)grow * lda + gk + 0];
                if (gk + 1 < K) t1 = A[(long long)grow * lda + gk + 1];
                if (gk + 2 < K) t2 = A[(long long)grow * lda + gk + 2];
                if (gk + 3 < K) t3 = A[(long long)grow * lda + gk + 3];
                av = make_float4(t0, t1, t2, t3);
            }
        }
        As[ak + 0][ar] = av.x; As[ak + 1][ar] = av.y;
        As[ak + 2][ar] = av.z; As[ak + 3][ar] = av.w;

        float4 bv = make_float4(0.f, 0.f, 0.f, 0.f);
        int gbk = k0 + br, gn = n0 + bn;
        if (gbk < K && gn + 3 < DOUT)
            bv = *(const float4*)(W + (long long)gbk * DOUT + gn);
        *(float4*)&Bs[br][bn] = bv;
        __syncthreads();

        #pragma unroll
        for (int kk = 0; kk < BK; ++kk) {
            float4 a4 = *(const float4*)&As[kk][ty << 2];
            float4 b4 = *(const float4*)&Bs[kk][tx << 2];
            float a[4] = {a4.x, a4.y, a4.z, a4.w};
            float b[4] = {b4.x, b4.y, b4.z, b4.w};
            #pragma unroll
            for (int i = 0; i < 4; ++i)
                #pragma unroll
                for (int j = 0; j < 4; ++j)
                    acc[i][j] = fmaf(a[i], b[j], acc[i][j]);
        }
        __syncthreads();
    }

    #pragma unroll
    for (int i = 0; i < 4; ++i) {
        int gm = m0 + (ty << 2) + i;
        if (gm >= N) continue;
        #pragma unroll
        for (int j = 0; j < 4; ++j) {
            int gn = n0 + (tx << 2) + j;
            if (gn < DOUT)
                C[(long long)gm * ldc + col0 + gn] = acc[i][j] + bias[gn];
        }
    }
}

// ======================= 128x128 GEMM (layer transforms) =====================
// K must be a multiple of 16, DOUT a multiple of 128 (true for all layer GEMMs)
#define GM 128
#define GN 128
#define GK 16

__global__ __launch_bounds__(256) void gemm128_kernel(
    const float* __restrict__ A, int lda,
    const float* __restrict__ W,
    const float* __restrict__ bias,
    float* __restrict__ C, int ldc, int col0,
    int N, int K, int DOUT)
{
    __shared__ float As[GK][GM + 4];
    __shared__ float Bs[GK][GN + 4];
    const int tid = threadIdx.x;
    const int tx = tid & 15, ty = tid >> 4;
    const int m0 = blockIdx.x * GM, n0 = blockIdx.y * GN;
    float acc[8][8] = {};

    const int ar = tid >> 1, ak = (tid & 1) << 3;   // 128 rows x (2 x 8k)
    const int br = tid >> 4, bn = (tid & 15) << 3;  // 16 k x (16 x 8 cols)

    for (int k0 = 0; k0 < K; k0 += GK) {
        int grow = m0 + ar, gk = k0 + ak;
        float4 a0 = make_float4(0.f, 0.f, 0.f, 0.f), a1 = a0;
        if (grow < N) {
            a0 = *(const float4*)(A + (long long)grow * lda + gk);
            a1 = *(const float4*)(A + (long long)grow * lda + gk + 4);
        }
        As[ak + 0][ar] = a0.x; As[ak + 1][ar] = a0.y;
        As[ak + 2][ar] = a0.z; As[ak + 3][ar] = a0.w;
        As[ak + 4][ar] = a1.x; As[ak + 5][ar] = a1.y;
        As[ak + 6][ar] = a1.z; As[ak + 7][ar] = a1.w;

        int gbk = k0 + br, gn = n0 + bn;
        float4 b0 = *(const float4*)(W + (long long)gbk * DOUT + gn);
        float4 b1 = *(const float4*)(W + (long long)gbk * DOUT + gn + 4);
        *(float4*)&Bs[br][bn] = b0;
        *(float4*)&Bs[br][bn + 4] = b1;
        __syncthreads();

        #pragma unroll
        for (int kk = 0; kk < GK; ++kk) {
            float4 aa0 = *(const float4*)&As[kk][ty << 2];
            float4 aa1 = *(const float4*)&As[kk][64 + (ty << 2)];
            float4 bb0 = *(const float4*)&Bs[kk][tx << 2];
            float4 bb1 = *(const float4*)&Bs[kk][64 + (tx << 2)];
            float a[8] = {aa0.x, aa0.y, aa0.z, aa0.w, aa1.x, aa1.y, aa1.z, aa1.w};
            float b[8] = {bb0.x, bb0.y, bb0.z, bb0.w, bb1.x, bb1.y, bb1.z, bb1.w};
            #pragma unroll
            for (int i = 0; i < 8; ++i)
                #pragma unroll
                for (int j = 0; j < 8; ++j)
                    acc[i][j] = fmaf(a[i], b[j], acc[i][j]);
        }
        __syncthreads();
    }

    #pragma unroll
    for (int half = 0; half < 2; ++half) {
        #pragma unroll
        for (int i = 0; i < 4; ++i) {
            int gm = m0 + half * 64 + (ty << 2) + i;
            if (gm >= N) continue;
            int ai = half * 4 + i;
            #pragma unroll
            for (int jh = 0; jh < 2; ++jh) {
                int gn = n0 + jh * 64 + (tx << 2);
                float4 r;
                r.x = acc[ai][jh * 4 + 0] + bias[gn + 0];
                r.y = acc[ai][jh * 4 + 1] + bias[gn + 1];
                r.z = acc[ai][jh * 4 + 2] + bias[gn + 2];
                r.w = acc[ai][jh * 4 + 3] + bias[gn + 3];
                *(float4*)(C + (long long)gm * ldc + col0 + gn) = r;
            }
        }
    }
}

// ====================== CSR-gather aggregation kernels =======================
// out[node] (=|+=) (1/deg) * sum_{e in CSR[node]} Wh[csr_src[e]]
template<int DOUT, bool ACC>
__global__ __launch_bounds__(256) void agg_wave_kernel(
    const float* __restrict__ Wh,
    const int* __restrict__ roff, const int* __restrict__ csr,
    float* __restrict__ out, int ldo, int col0, int N)
{
    constexpr int CT = DOUT / 4;       // lanes covering the feature dim
    constexpr int NPB = 256 / CT;      // nodes per block
    const int node = blockIdx.x * NPB + threadIdx.x / CT;
    if (node >= N) return;
    const int c = threadIdx.x % CT;
    const int beg = roff[node], end = roff[node + 1];
    float sx = 0.f, sy = 0.f, sz = 0.f, sw = 0.f;
    for (int e = beg; e < end; ++e) {
        const int s = csr[e];
        const float4 v = *(const float4*)(Wh + (long long)s * DOUT + (c << 2));
        sx += v.x; sy += v.y; sz += v.z; sw += v.w;
    }
    const int deg = end - beg;
    const float sc = deg > 0 ? 1.0f / (float)deg : 0.0f;
    float* po = out + (long long)node * ldo + col0 + (c << 2);
    float4 r; r.x = sx * sc; r.y = sy * sc; r.z = sz * sc; r.w = sw * sc;
    if (ACC) {
        const float4 o = *(const float4*)po;
        r.x += o.x; r.y += o.y; r.z += o.z; r.w += o.w;
    }
    *(float4*)po = r;
}

// block-per-node variant for high-degree, tiny-N destinations (pt / ft)
template<int DOUT, bool ACC>
__global__ __launch_bounds__(256) void agg_block_kernel(
    const float* __restrict__ Wh,
    const int* __restrict__ roff, const int* __restrict__ csr,
    float* __restrict__ out, int ldo, int col0, int N)
{
    constexpr int CT = DOUT / 4;
    constexpr int EP = 256 / CT;       // edge-parallel groups
    const int node = blockIdx.x;
    if (node >= N) return;
    const int c = threadIdx.x % CT;
    const int g = threadIdx.x / CT;
    const int beg = roff[node], end = roff[node + 1];
    float sx = 0.f, sy = 0.f, sz = 0.f, sw = 0.f;
    for (int e = beg + g; e < end; e += EP) {
        const int s = csr[e];
        const float4 v = *(const float4*)(Wh + (long long)s * DOUT + (c << 2));
        sx += v.x; sy += v.y; sz += v.z; sw += v.w;
    }
    __shared__ float4 red[256];
    red[threadIdx.x] = make_float4(sx, sy, sz, sw);
    __syncthreads();
    if (g == 0) {
        #pragma unroll
        for (int k = 1; k < EP; ++k) {
            const float4 v = red[k * CT + c];
            sx += v.x; sy += v.y; sz += v.z; sw += v.w;
        }
        const int deg = end - beg;
        const float sc = deg > 0 ? 1.0f / (float)deg : 0.0f;
        float* po = out + (long long)node * ldo + col0 + (c << 2);
        float4 r; r.x = sx * sc; r.y = sy * sc; r.z = sz * sc; r.w = sw * sc;
        if (ACC) {
            const float4 o = *(const float4*)po;
            r.x += o.x; r.y += o.y; r.z += o.z; r.w += o.w;
        }
        *(float4*)po = r;
    }
}

// ============================ CSR build helpers ==============================
__global__ void zero_i32_kernel(int* __restrict__ p, int n)
{
    int i = blockIdx.x * blockDim.x + threadIdx.x;
    if (i < n) p[i] = 0;
}

__global__ void count_kernel(const int* __restrict__ dst, int E, int* __restrict__ cnt)
{
    int i = blockIdx.x * blockDim.x + threadIdx.x;
    if (i < E) atomicAdd(&cnt[dst[i]], 1);
}

struct ScanParams { int off[8]; int N[8]; };

// one block per etype: exclusive scan of cnt -> row offsets (incl. total at [N])
__global__ __launch_bounds__(1024) void scan8_kernel(
    const int* __restrict__ cnt_all, int* __restrict__ roff_all, ScanParams p)
{
    const int et = blockIdx.x;
    const int* cnt = cnt_all + p.off[et];
    int* roff = roff_all + p.off[et] + et;   // +et: each etype has one extra slot
    const int N = p.N[et];
    __shared__ int sh[1024];
    __shared__ int carry_sh;
    if (threadIdx.x == 0) carry_sh = 0;
    __syncthreads();
    for (int base = 0; base < N; base += 1024) {
        const int i = base + threadIdx.x;
        const int v = (i < N) ? cnt[i] : 0;
        sh[threadIdx.x] = v;
        __syncthreads();
        int incl = v;
        for (int ofs = 1; ofs < 1024; ofs <<= 1) {
            const int t = (threadIdx.x >= (unsigned)ofs) ? sh[threadIdx.x - ofs] : 0;
            __syncthreads();
            incl += t;
            sh[threadIdx.x] = incl;
            __syncthreads();
        }
        const int carry = carry_sh;
        if (i < N) roff[i] = carry + incl - v;
        __syncthreads();
        if (threadIdx.x == 1023) carry_sh = carry + incl;
        __syncthreads();
    }
    if (threadIdx.x == 0) roff[N] = carry_sh;
}

__global__ void fill_kernel(const int* __restrict__ src, const int* __restrict__ dst,
                            int E, const int* __restrict__ roff,
                            int* __restrict__ cur, int* __restrict__ csr)
{
    int i = blockIdx.x * blockDim.x + threadIdx.x;
    if (i < E) {
        const int d = dst[i];
        const int pos = atomicAdd(&cur[d], 1);
        csr[roff[d] + pos] = src[i];
    }
}

// ============================== misc kernels =================================
__global__ void bcast_kernel(const float* __restrict__ emb, float* __restrict__ Fp,
                             int ld, int N)
{
    int idx = blockIdx.x * blockDim.x + threadIdx.x;
    if (idx >= N * 128) return;
    int r = idx >> 7, c = idx & 127;
    Fp[(long long)r * ld + c] = emb[c];
}

__global__ void decoder_kernel(const float* __restrict__ H, int ld, int N,
                               const float* __restrict__ Wd,
                               const float* __restrict__ bd,
                               float* __restrict__ logits, float* __restrict__ soft)
{
    int n = blockIdx.x * blockDim.x + threadIdx.x;
    if (n >= N) return;
    const float* h = H + (long long)n * ld;
    float s0 = bd[0], s1 = bd[1];
    #pragma unroll
    for (int k = 0; k < 128; k += 4) {
        float4 hv = *(const float4*)(h + k);
        s0 = fmaf(hv.x, Wd[2 * (k + 0) + 0], s0); s1 = fmaf(hv.x, Wd[2 * (k + 0) + 1], s1);
        s0 = fmaf(hv.y, Wd[2 * (k + 1) + 0], s0); s1 = fmaf(hv.y, Wd[2 * (k + 1) + 1], s1);
        s0 = fmaf(hv.z, Wd[2 * (k + 2) + 0], s0); s1 = fmaf(hv.z, Wd[2 * (k + 2) + 1], s1);
        s0 = fmaf(hv.w, Wd[2 * (k + 3) + 0], s0); s1 = fmaf(hv.w, Wd[2 * (k + 3) + 1], s1);
    }
    logits[2 * n + 0] = s0;
    logits[2 * n + 1] = s1;
    float m = fmaxf(s0, s1);
    float e0 = expf(s0 - m), e1 = expf(s1 - m);
    float invs = 1.f / (e0 + e1);
    soft[2 * n + 0] = e0 * invs;
    soft[2 * n + 1] = e1 * invs;
}

// ================================== host =====================================
extern "C" void kernel_launch(void* const* d_in, const int* in_sizes, int n_in,
                              void* d_out, int out_size, void* d_ws, size_t ws_size,
                              hipStream_t stream)
{
    enum { CFG = 0, AST = 1, PT = 2, FT = 3 };
    const int Nnt[4] = {20000, 100000, 50, 10};
    const int stp[8] = {CFG, AST, AST, CFG, PT, CFG, FT, CFG};
    const int dtp[8] = {CFG, AST, CFG, AST, CFG, PT, CFG, FT};
    // first etype writing each dst type (i = 0:cfg, 1:ast, 5:pt, 7:ft)
    const bool firstw[8] = {true, true, false, false, false, true, false, true};

    const float* cfg_label   = (const float*)d_in[0];
    const float* cfg_content = (const float*)d_in[1];
    const float* ast_label   = (const float*)d_in[2];
    const float* ast_content = (const float*)d_in[3];
    const int* esrc[8]; const int* edst[8]; int E[8];
    for (int i = 0; i < 8; ++i) {
        esrc[i] = (const int*)d_in[4 + 2 * i];
        edst[i] = (const int*)d_in[5 + 2 * i];
        E[i]    = in_sizes[4 + 2 * i];
    }
    const float* W_cfg_lab = (const float*)d_in[20]; const float* b_cfg_lab = (const float*)d_in[21];
    const float* W_cfg_con = (const float*)d_in[22]; const float* b_cfg_con = (const float*)d_in[23];
    const float* W_ast_lab = (const float*)d_in[24]; const float* b_ast_lab = (const float*)d_in[25];
    const float* W_ast_con = (const float*)d_in[26]; const float* b_ast_con = (const float*)d_in[27];
    const float* ptest_emb = (const float*)d_in[28];
    const float* ftest_emb = (const float*)d_in[29];
    const float* Wl[5] = {(const float*)d_in[30], (const float*)d_in[32], (const float*)d_in[34],
                          (const float*)d_in[36], (const float*)d_in[38]};
    const float* bl[5] = {(const float*)d_in[31], (const float*)d_in[33], (const float*)d_in[35],
                          (const float*)d_in[37], (const float*)d_in[39]};
    const float* W_dec = (const float*)d_in[40];
    const float* b_dec = (const float*)d_in[41];

    // -------- workspace carve --------
    char* ws = (char*)d_ws;
    size_t off = 0;
    auto carve = [&](size_t bytes) -> void* {
        void* p = ws + off;
        off = (off + bytes + 255) & ~(size_t)255;
        return p;
    };
    float* F[4];  float* F2[4];
    F[CFG]  = (float*)carve((size_t)20000  * 512 * 4);
    F[AST]  = (float*)carve((size_t)100000 * 512 * 4);
    F[PT]   = (float*)carve((size_t)50     * 512 * 4);
    F[FT]   = (float*)carve((size_t)10     * 512 * 4);
    F2[CFG] = (float*)carve((size_t)20000  * 256 * 4);
    F2[AST] = (float*)carve((size_t)100000 * 256 * 4);
    F2[PT]  = (float*)carve((size_t)50     * 256 * 4);
    F2[FT]  = (float*)carve((size_t)10     * 256 * 4);
    float* Wh = (float*)carve((size_t)100000 * 256 * 4);

    int Nd[8], cntoff[8], roffoff[8], csroff[8];
    int totc = 0, tote = 0;
    for (int i = 0; i < 8; ++i) {
        Nd[i] = Nnt[dtp[i]];
        cntoff[i] = totc; roffoff[i] = totc + i; csroff[i] = tote;
        totc += Nd[i]; tote += E[i];
    }
    int* cnt_all  = (int*)carve((size_t)totc * 4);
    int* cur_all  = (int*)carve((size_t)totc * 4);
    int* roff_all = (int*)carve((size_t)(totc + 8) * 4);
    int* csr_all  = (int*)carve((size_t)tote * 4);

    // -------- CSR build (once per call; graph is static across layers) -------
    zero_i32_kernel<<<(totc + 255) / 256, 256, 0, stream>>>(cnt_all, totc);
    zero_i32_kernel<<<(totc + 255) / 256, 256, 0, stream>>>(cur_all, totc);
    for (int i = 0; i < 8; ++i)
        count_kernel<<<(E[i] + 255) / 256, 256, 0, stream>>>(edst[i], E[i], cnt_all + cntoff[i]);
    ScanParams sp;
    for (int i = 0; i < 8; ++i) { sp.off[i] = cntoff[i]; sp.N[i] = Nd[i]; }
    scan8_kernel<<<8, 1024, 0, stream>>>(cnt_all, roff_all, sp);
    for (int i = 0; i < 8; ++i)
        fill_kernel<<<(E[i] + 255) / 256, 256, 0, stream>>>(
            esrc[i], edst[i], E[i], roff_all + roffoff[i], cur_all + cntoff[i],
            csr_all + csroff[i]);

    // -------- encoders: h0 into F[:,0:128] (stride 512) --------
    {
        dim3 g1((20000 + BM - 1) / BM, 1), g2((100000 + BM - 1) / BM, 1);
        gemm_bias_kernel<<<g1, 256, 0, stream>>>(cfg_label, 80, W_cfg_lab, b_cfg_lab,
                                                 F[CFG], 512, 0, 20000, 80, 64);
        gemm_bias_kernel<<<g1, 256, 0, stream>>>(cfg_content, 300, W_cfg_con, b_cfg_con,
                                                 F[CFG], 512, 64, 20000, 300, 64);
        gemm_bias_kernel<<<g2, 256, 0, stream>>>(ast_label, 80, W_ast_lab, b_ast_lab,
                                                 F[AST], 512, 0, 100000, 80, 64);
        gemm_bias_kernel<<<g2, 256, 0, stream>>>(ast_content, 300, W_ast_con, b_ast_con,
                                                 F[AST], 512, 64, 100000, 300, 64);
    }
    bcast_kernel<<<(50 * 128 + 255) / 256, 256, 0, stream>>>(ptest_emb, F[PT], 512, 50);
    bcast_kernel<<<(10 * 128 + 255) / 256, 256, 0, stream>>>(ftest_emb, F[FT], 512, 10);

    // -------- aggregation dispatcher --------
    auto launch_agg = [&](int i, int dout, float* outp, int ldo, int col0) {
        const int* roff = roff_all + roffoff[i];
        const int* csr  = csr_all + csroff[i];
        const int Ndst  = Nd[i];
        const bool acc  = !firstw[i];
        const bool blockmode = (i == 5 || i == 7);   // pt / ft dst: huge degree
        if (dout == 128) {
            if (blockmode) {
                if (acc) agg_block_kernel<128, true ><<<Ndst, 256, 0, stream>>>(Wh, roff, csr, outp, ldo, col0, Ndst);
                else     agg_block_kernel<128, false><<<Ndst, 256, 0, stream>>>(Wh, roff, csr, outp, ldo, col0, Ndst);
            } else {
                int grid = (Ndst + 7) / 8;
                if (acc) agg_wave_kernel<128, true ><<<grid, 256, 0, stream>>>(Wh, roff, csr, outp, ldo, col0, Ndst);
                else     agg_wave_kernel<128, false><<<grid, 256, 0, stream>>>(Wh, roff, csr, outp, ldo, col0, Ndst);
            }
        } else {
            if (blockmode) {
                if (acc) agg_block_kernel<256, true ><<<Ndst, 256, 0, stream>>>(Wh, roff, csr, outp, ldo, col0, Ndst);
                else     agg_block_kernel<256, false><<<Ndst, 256, 0, stream>>>(Wh, roff, csr, outp, ldo, col0, Ndst);
            } else {
                int grid = (Ndst + 3) / 4;
                if (acc) agg_wave_kernel<256, true ><<<grid, 256, 0, stream>>>(Wh, roff, csr, outp, ldo, col0, Ndst);
                else     agg_wave_kernel<256, false><<<grid, 256, 0, stream>>>(Wh, roff, csr, outp, ldo, col0, Ndst);
            }
        }
    };

    // -------- one hetero-GCN layer --------
    auto run_layer = [&](const float* Wstack, const float* bstack, int din, int dout,
                         float* const* inB, int ldin, float* const* outB, int ldout,
                         int colout) {
        for (int i = 0; i < 8; ++i) {
            const int s = stp[i], d = dtp[i];
            dim3 g((Nnt[s] + GM - 1) / GM, dout / GN);
            gemm128_kernel<<<g, 256, 0, stream>>>(
                inB[s], ldin, Wstack + (size_t)i * din * dout, bstack + (size_t)i * dout,
                Wh, dout, 0, Nnt[s], din, dout);
            launch_agg(i, dout, outB[d], ldout, colout);
        }
    };

    // L1: F[:,0:128] -> F2[:,0:128]
    run_layer(Wl[0], bl[0], 128, 128, F,  512, F2, 256, 0);
    // L2: F2[:,0:128] -> F2[:,128:256]  (concat -> F2[:,0:256])
    run_layer(Wl[1], bl[1], 128, 128, F2, 256, F2, 256, 128);
    // L3: F2[:,0:256] -> F[:,0:256]
    run_layer(Wl[2], bl[2], 256, 256, F2, 256, F,  512, 0);
    // L4: F[:,0:256] -> F[:,256:512]   (concat -> F[:,0:512])
    run_layer(Wl[3], bl[3], 256, 256, F,  512, F,  512, 256);
    // L5: F[:,0:512] -> F2[:,0:128]
    run_layer(Wl[4], bl[4], 512, 128, F,  512, F2, 256, 0);

    // -------- decoder + softmax --------
    float* out = (float*)d_out;
    decoder_kernel<<<(20000 + 255) / 256, 256, 0, stream>>>(
        F2[CFG], 256, 20000, W_dec, b_dec, out + 0, out + 40000);
    decoder_kernel<<<(100000 + 255) / 256, 256, 0, stream>>>(
        F2[AST], 256, 100000, W_dec, b_dec, out + 80000, out + 280000);
}

// Round 4
// 4755.125 us; speedup vs baseline: 3.4612x; 1.4798x over previous
//
#include <hip/hip_runtime.h>

// ============================ 64-wide GEMM (encoders) ========================
#define BM 64
#define BN 64
#define BK 16

__global__ __launch_bounds__(256) void gemm_bias_kernel(
    const float* __restrict__ A, int lda,
    const float* __restrict__ W,        // [K, DOUT] row-major
    const float* __restrict__ bias,     // [DOUT]
    float* __restrict__ C, int ldc, int col0,
    int N, int K, int DOUT)
{
    __shared__ float As[BK][BM + 4];
    __shared__ float Bs[BK][BN + 4];
    const int tid = threadIdx.x;
    const int tx = tid & 15, ty = tid >> 4;
    const int m0 = blockIdx.x * BM, n0 = blockIdx.y * BN;
    float acc[4][4] = {};
    const int ar = tid >> 2, ak = (tid & 3) << 2;   // A tile: 64 rows x 16 k
    const int br = tid >> 4, bn = (tid & 15) << 2;  // B tile: 16 k x 64 cols

    for (int k0 = 0; k0 < K; k0 += BK) {
        float4 av = make_float4(0.f, 0.f, 0.f, 0.f);
        int grow = m0 + ar, gk = k0 + ak;
        if (grow < N) {
            if (gk + 3 < K) {
                av = *(const float4*)(A + (long long)grow * lda + gk);
            } else {
                float t0 = 0.f, t1 = 0.f, t2 = 0.f, t3 = 0.f;
                if (gk + 0 < K) t0 = A[(long long)grow * lda + gk + 0];
                if (gk + 1 < K) t1 = A[(long long)grow * lda + gk + 1];
                if (gk + 2 < K) t2 = A[(long long)grow * lda + gk + 2];
                if (gk + 3 < K) t3 = A[(long long)grow * lda + gk + 3];
                av = make_float4(t0, t1, t2, t3);
            }
        }
        As[ak + 0][ar] = av.x; As[ak + 1][ar] = av.y;
        As[ak + 2][ar] = av.z; As[ak + 3][ar] = av.w;

        float4 bv = make_float4(0.f, 0.f, 0.f, 0.f);
        int gbk = k0 + br, gn = n0 + bn;
        if (gbk < K && gn + 3 < DOUT)
            bv = *(const float4*)(W + (long long)gbk * DOUT + gn);
        *(float4*)&Bs[br][bn] = bv;
        __syncthreads();

        #pragma unroll
        for (int kk = 0; kk < BK; ++kk) {
            float4 a4 = *(const float4*)&As[kk][ty << 2];
            float4 b4 = *(const float4*)&Bs[kk][tx << 2];
            float a[4] = {a4.x, a4.y, a4.z, a4.w};
            float b[4] = {b4.x, b4.y, b4.z, b4.w};
            #pragma unroll
            for (int i = 0; i < 4; ++i)
                #pragma unroll
                for (int j = 0; j < 4; ++j)
                    acc[i][j] = fmaf(a[i], b[j], acc[i][j]);
        }
        __syncthreads();
    }

    #pragma unroll
    for (int i = 0; i < 4; ++i) {
        int gm = m0 + (ty << 2) + i;
        if (gm >= N) continue;
        #pragma unroll
        for (int j = 0; j < 4; ++j) {
            int gn = n0 + (tx << 2) + j;
            if (gn < DOUT)
                C[(long long)gm * ldc + col0 + gn] = acc[i][j] + bias[gn];
        }
    }
}

// ======================= 128x128 GEMM (layer transforms) =====================
#define GM 128
#define GN 128
#define GK 16

__global__ __launch_bounds__(256) void gemm128_kernel(
    const float* __restrict__ A, int lda,
    const float* __restrict__ W,
    const float* __restrict__ bias,
    float* __restrict__ C, int ldc, int col0,
    int N, int K, int DOUT)
{
    __shared__ float As[GK][GM + 4];
    __shared__ float Bs[GK][GN + 4];
    const int tid = threadIdx.x;
    const int tx = tid & 15, ty = tid >> 4;
    const int m0 = blockIdx.x * GM, n0 = blockIdx.y * GN;
    float acc[8][8] = {};

    const int ar = tid >> 1, ak = (tid & 1) << 3;   // 128 rows x (2 x 8k)
    const int br = tid >> 4, bn = (tid & 15) << 3;  // 16 k x (16 x 8 cols)

    for (int k0 = 0; k0 < K; k0 += GK) {
        int grow = m0 + ar, gk = k0 + ak;
        float4 a0 = make_float4(0.f, 0.f, 0.f, 0.f), a1 = a0;
        if (grow < N) {
            a0 = *(const float4*)(A + (long long)grow * lda + gk);
            a1 = *(const float4*)(A + (long long)grow * lda + gk + 4);
        }
        As[ak + 0][ar] = a0.x; As[ak + 1][ar] = a0.y;
        As[ak + 2][ar] = a0.z; As[ak + 3][ar] = a0.w;
        As[ak + 4][ar] = a1.x; As[ak + 5][ar] = a1.y;
        As[ak + 6][ar] = a1.z; As[ak + 7][ar] = a1.w;

        int gbk = k0 + br, gn = n0 + bn;
        float4 b0 = *(const float4*)(W + (long long)gbk * DOUT + gn);
        float4 b1 = *(const float4*)(W + (long long)gbk * DOUT + gn + 4);
        *(float4*)&Bs[br][bn] = b0;
        *(float4*)&Bs[br][bn + 4] = b1;
        __syncthreads();

        #pragma unroll
        for (int kk = 0; kk < GK; ++kk) {
            float4 aa0 = *(const float4*)&As[kk][ty << 2];
            float4 aa1 = *(const float4*)&As[kk][64 + (ty << 2)];
            float4 bb0 = *(const float4*)&Bs[kk][tx << 2];
            float4 bb1 = *(const float4*)&Bs[kk][64 + (tx << 2)];
            float a[8] = {aa0.x, aa0.y, aa0.z, aa0.w, aa1.x, aa1.y, aa1.z, aa1.w};
            float b[8] = {bb0.x, bb0.y, bb0.z, bb0.w, bb1.x, bb1.y, bb1.z, bb1.w};
            #pragma unroll
            for (int i = 0; i < 8; ++i)
                #pragma unroll
                for (int j = 0; j < 8; ++j)
                    acc[i][j] = fmaf(a[i], b[j], acc[i][j]);
        }
        __syncthreads();
    }

    #pragma unroll
    for (int half = 0; half < 2; ++half) {
        #pragma unroll
        for (int i = 0; i < 4; ++i) {
            int gm = m0 + half * 64 + (ty << 2) + i;
            if (gm >= N) continue;
            int ai = half * 4 + i;
            #pragma unroll
            for (int jh = 0; jh < 2; ++jh) {
                int gn = n0 + jh * 64 + (tx << 2);
                float4 r;
                r.x = acc[ai][jh * 4 + 0] + bias[gn + 0];
                r.y = acc[ai][jh * 4 + 1] + bias[gn + 1];
                r.z = acc[ai][jh * 4 + 2] + bias[gn + 2];
                r.w = acc[ai][jh * 4 + 3] + bias[gn + 3];
                *(float4*)(C + (long long)gm * ldc + col0 + gn) = r;
            }
        }
    }
}

// ====================== CSR-gather aggregation kernels =======================
// out[node] (=|+=) (1/deg) * sum_{e in CSR[node]} Wh[csr_src[e]]
template<int DOUT, bool ACC>
__global__ __launch_bounds__(256) void agg_wave_kernel(
    const float* __restrict__ Wh,
    const int* __restrict__ roff, const int* __restrict__ csr,
    float* __restrict__ out, int ldo, int col0, int N)
{
    constexpr int CT = DOUT / 4;       // lanes covering the feature dim
    constexpr int NPB = 256 / CT;      // nodes per block
    const int node = blockIdx.x * NPB + threadIdx.x / CT;
    if (node >= N) return;
    const int c = threadIdx.x % CT;
    const int beg = roff[node], end = roff[node + 1];
    float sx = 0.f, sy = 0.f, sz = 0.f, sw = 0.f;
    for (int e = beg; e < end; ++e) {
        const int s = csr[e];
        const float4 v = *(const float4*)(Wh + (long long)s * DOUT + (c << 2));
        sx += v.x; sy += v.y; sz += v.z; sw += v.w;
    }
    const int deg = end - beg;
    const float sc = deg > 0 ? 1.0f / (float)deg : 0.0f;
    float* po = out + (long long)node * ldo + col0 + (c << 2);
    float4 r; r.x = sx * sc; r.y = sy * sc; r.z = sz * sc; r.w = sw * sc;
    if (ACC) {
        const float4 o = *(const float4*)po;
        r.x += o.x; r.y += o.y; r.z += o.z; r.w += o.w;
    }
    *(float4*)po = r;
}

// ---- multi-block partial aggregation for tiny-N / huge-degree dsts (pt/ft) --
// grid = N * SEGS blocks; partial sums atomically accumulated into P[N][DOUT]
template<int DOUT>
__global__ __launch_bounds__(256) void agg_part_kernel(
    const float* __restrict__ Wh,
    const int* __restrict__ roff, const int* __restrict__ csr,
    float* __restrict__ P, int SEGS)
{
    constexpr int CT = DOUT / 4;       // lanes covering feature dim
    constexpr int EP = 256 / CT;       // edge-parallel groups per block
    const int node = blockIdx.x / SEGS;
    const int seg  = blockIdx.x % SEGS;
    const int c = threadIdx.x % CT;
    const int g = threadIdx.x / CT;
    const int beg = roff[node], end = roff[node + 1];
    float sx = 0.f, sy = 0.f, sz = 0.f, sw = 0.f;
    for (int e = beg + seg * EP + g; e < end; e += SEGS * EP) {
        const int s = csr[e];
        const float4 v = *(const float4*)(Wh + (long long)s * DOUT + (c << 2));
        sx += v.x; sy += v.y; sz += v.z; sw += v.w;
    }
    __shared__ float4 red[256];
    red[threadIdx.x] = make_float4(sx, sy, sz, sw);
    __syncthreads();
    if (g == 0) {
        #pragma unroll
        for (int k = 1; k < EP; ++k) {
            const float4 v = red[k * CT + c];
            sx += v.x; sy += v.y; sz += v.z; sw += v.w;
        }
        float* pp = P + (long long)node * DOUT + (c << 2);
        atomicAdd(pp + 0, sx);
        atomicAdd(pp + 1, sy);
        atomicAdd(pp + 2, sz);
        atomicAdd(pp + 3, sw);
    }
}

// finalize: out[n][col0+c] = P[n][c] / deg[n]   (pt/ft are sole writers)
__global__ void agg_fin_kernel(const float* __restrict__ P,
                               const int* __restrict__ roff,
                               float* __restrict__ out, int ldo, int col0,
                               int N, int DOUT)
{
    int idx = blockIdx.x * blockDim.x + threadIdx.x;
    if (idx >= N * DOUT) return;
    int n = idx / DOUT, c = idx % DOUT;
    int deg = roff[n + 1] - roff[n];
    float sc = deg > 0 ? 1.0f / (float)deg : 0.0f;
    out[(long long)n * ldo + col0 + c] = P[idx] * sc;
}

__global__ void zero_f32_kernel(float* __restrict__ p, int n)
{
    int i = blockIdx.x * blockDim.x + threadIdx.x;
    if (i < n) p[i] = 0.f;
}

// ============================ CSR build helpers ==============================
__global__ void zero_i32_kernel(int* __restrict__ p, int n)
{
    int i = blockIdx.x * blockDim.x + threadIdx.x;
    if (i < n) p[i] = 0;
}

__global__ void count_kernel(const int* __restrict__ dst, int E, int* __restrict__ cnt)
{
    int i = blockIdx.x * blockDim.x + threadIdx.x;
    if (i < E) atomicAdd(&cnt[dst[i]], 1);
}

struct ScanParams { int off[8]; int N[8]; };

__global__ __launch_bounds__(1024) void scan8_kernel(
    const int* __restrict__ cnt_all, int* __restrict__ roff_all, ScanParams p)
{
    const int et = blockIdx.x;
    const int* cnt = cnt_all + p.off[et];
    int* roff = roff_all + p.off[et] + et;
    const int N = p.N[et];
    __shared__ int sh[1024];
    __shared__ int carry_sh;
    if (threadIdx.x == 0) carry_sh = 0;
    __syncthreads();
    for (int base = 0; base < N; base += 1024) {
        const int i = base + threadIdx.x;
        const int v = (i < N) ? cnt[i] : 0;
        sh[threadIdx.x] = v;
        __syncthreads();
        int incl = v;
        for (int ofs = 1; ofs < 1024; ofs <<= 1) {
            const int t = (threadIdx.x >= (unsigned)ofs) ? sh[threadIdx.x - ofs] : 0;
            __syncthreads();
            incl += t;
            sh[threadIdx.x] = incl;
            __syncthreads();
        }
        const int carry = carry_sh;
        if (i < N) roff[i] = carry + incl - v;
        __syncthreads();
        if (threadIdx.x == 1023) carry_sh = carry + incl;
        __syncthreads();
    }
    if (threadIdx.x == 0) roff[N] = carry_sh;
}

__global__ void fill_kernel(const int* __restrict__ src, const int* __restrict__ dst,
                            int E, const int* __restrict__ roff,
                            int* __restrict__ cur, int* __restrict__ csr)
{
    int i = blockIdx.x * blockDim.x + threadIdx.x;
    if (i < E) {
        const int d = dst[i];
        const int pos = atomicAdd(&cur[d], 1);
        csr[roff[d] + pos] = src[i];
    }
}

// ============================== misc kernels =================================
__global__ void bcast_kernel(const float* __restrict__ emb, float* __restrict__ Fp,
                             int ld, int N)
{
    int idx = blockIdx.x * blockDim.x + threadIdx.x;
    if (idx >= N * 128) return;
    int r = idx >> 7, c = idx & 127;
    Fp[(long long)r * ld + c] = emb[c];
}

__global__ void decoder_kernel(const float* __restrict__ H, int ld, int N,
                               const float* __restrict__ Wd,
                               const float* __restrict__ bd,
                               float* __restrict__ logits, float* __restrict__ soft)
{
    int n = blockIdx.x * blockDim.x + threadIdx.x;
    if (n >= N) return;
    const float* h = H + (long long)n * ld;
    float s0 = bd[0], s1 = bd[1];
    #pragma unroll
    for (int k = 0; k < 128; k += 4) {
        float4 hv = *(const float4*)(h + k);
        s0 = fmaf(hv.x, Wd[2 * (k + 0) + 0], s0); s1 = fmaf(hv.x, Wd[2 * (k + 0) + 1], s1);
        s0 = fmaf(hv.y, Wd[2 * (k + 1) + 0], s0); s1 = fmaf(hv.y, Wd[2 * (k + 1) + 1], s1);
        s0 = fmaf(hv.z, Wd[2 * (k + 2) + 0], s0); s1 = fmaf(hv.z, Wd[2 * (k + 2) + 1], s1);
        s0 = fmaf(hv.w, Wd[2 * (k + 3) + 0], s0); s1 = fmaf(hv.w, Wd[2 * (k + 3) + 1], s1);
    }
    logits[2 * n + 0] = s0;
    logits[2 * n + 1] = s1;
    float m = fmaxf(s0, s1);
    float e0 = expf(s0 - m), e1 = expf(s1 - m);
    float invs = 1.f / (e0 + e1);
    soft[2 * n + 0] = e0 * invs;
    soft[2 * n + 1] = e1 * invs;
}

// ================================== host =====================================
extern "C" void kernel_launch(void* const* d_in, const int* in_sizes, int n_in,
                              void* d_out, int out_size, void* d_ws, size_t ws_size,
                              hipStream_t stream)
{
    enum { CFG = 0, AST = 1, PT = 2, FT = 3 };
    const int Nnt[4] = {20000, 100000, 50, 10};
    const int stp[8] = {CFG, AST, AST, CFG, PT, CFG, FT, CFG};
    const int dtp[8] = {CFG, AST, CFG, AST, CFG, PT, CFG, FT};
    const bool firstw[8] = {true, true, false, false, false, true, false, true};

    const float* cfg_label   = (const float*)d_in[0];
    const float* cfg_content = (const float*)d_in[1];
    const float* ast_label   = (const float*)d_in[2];
    const float* ast_content = (const float*)d_in[3];
    const int* esrc[8]; const int* edst[8]; int E[8];
    for (int i = 0; i < 8; ++i) {
        esrc[i] = (const int*)d_in[4 + 2 * i];
        edst[i] = (const int*)d_in[5 + 2 * i];
        E[i]    = in_sizes[4 + 2 * i];
    }
    const float* W_cfg_lab = (const float*)d_in[20]; const float* b_cfg_lab = (const float*)d_in[21];
    const float* W_cfg_con = (const float*)d_in[22]; const float* b_cfg_con = (const float*)d_in[23];
    const float* W_ast_lab = (const float*)d_in[24]; const float* b_ast_lab = (const float*)d_in[25];
    const float* W_ast_con = (const float*)d_in[26]; const float* b_ast_con = (const float*)d_in[27];
    const float* ptest_emb = (const float*)d_in[28];
    const float* ftest_emb = (const float*)d_in[29];
    const float* Wl[5] = {(const float*)d_in[30], (const float*)d_in[32], (const float*)d_in[34],
                          (const float*)d_in[36], (const float*)d_in[38]};
    const float* bl[5] = {(const float*)d_in[31], (const float*)d_in[33], (const float*)d_in[35],
                          (const float*)d_in[37], (const float*)d_in[39]};
    const float* W_dec = (const float*)d_in[40];
    const float* b_dec = (const float*)d_in[41];

    // -------- workspace carve --------
    char* ws = (char*)d_ws;
    size_t off = 0;
    auto carve = [&](size_t bytes) -> void* {
        void* p = ws + off;
        off = (off + bytes + 255) & ~(size_t)255;
        return p;
    };
    float* F[4];  float* F2[4];
    F[CFG]  = (float*)carve((size_t)20000  * 512 * 4);
    F[AST]  = (float*)carve((size_t)100000 * 512 * 4);
    F[PT]   = (float*)carve((size_t)50     * 512 * 4);
    F[FT]   = (float*)carve((size_t)10     * 512 * 4);
    F2[CFG] = (float*)carve((size_t)20000  * 256 * 4);
    F2[AST] = (float*)carve((size_t)100000 * 256 * 4);
    F2[PT]  = (float*)carve((size_t)50     * 256 * 4);
    F2[FT]  = (float*)carve((size_t)10     * 256 * 4);
    float* Wh = (float*)carve((size_t)100000 * 256 * 4);
    float* P  = (float*)carve((size_t)50 * 256 * 4);   // pt/ft partial staging

    int Nd[8], cntoff[8], roffoff[8], csroff[8];
    int totc = 0, tote = 0;
    for (int i = 0; i < 8; ++i) {
        Nd[i] = Nnt[dtp[i]];
        cntoff[i] = totc; roffoff[i] = totc + i; csroff[i] = tote;
        totc += Nd[i]; tote += E[i];
    }
    int* cnt_all  = (int*)carve((size_t)totc * 4);
    int* cur_all  = (int*)carve((size_t)totc * 4);
    int* roff_all = (int*)carve((size_t)(totc + 8) * 4);
    int* csr_all  = (int*)carve((size_t)tote * 4);

    // -------- CSR build (once per call) --------
    zero_i32_kernel<<<(totc + 255) / 256, 256, 0, stream>>>(cnt_all, totc);
    zero_i32_kernel<<<(totc + 255) / 256, 256, 0, stream>>>(cur_all, totc);
    for (int i = 0; i < 8; ++i)
        count_kernel<<<(E[i] + 255) / 256, 256, 0, stream>>>(edst[i], E[i], cnt_all + cntoff[i]);
    ScanParams sp;
    for (int i = 0; i < 8; ++i) { sp.off[i] = cntoff[i]; sp.N[i] = Nd[i]; }
    scan8_kernel<<<8, 1024, 0, stream>>>(cnt_all, roff_all, sp);
    for (int i = 0; i < 8; ++i)
        fill_kernel<<<(E[i] + 255) / 256, 256, 0, stream>>>(
            esrc[i], edst[i], E[i], roff_all + roffoff[i], cur_all + cntoff[i],
            csr_all + csroff[i]);

    // -------- encoders: h0 into F[:,0:128] (stride 512) --------
    {
        dim3 g1((20000 + BM - 1) / BM, 1), g2((100000 + BM - 1) / BM, 1);
        gemm_bias_kernel<<<g1, 256, 0, stream>>>(cfg_label, 80, W_cfg_lab, b_cfg_lab,
                                                 F[CFG], 512, 0, 20000, 80, 64);
        gemm_bias_kernel<<<g1, 256, 0, stream>>>(cfg_content, 300, W_cfg_con, b_cfg_con,
                                                 F[CFG], 512, 64, 20000, 300, 64);
        gemm_bias_kernel<<<g2, 256, 0, stream>>>(ast_label, 80, W_ast_lab, b_ast_lab,
                                                 F[AST], 512, 0, 100000, 80, 64);
        gemm_bias_kernel<<<g2, 256, 0, stream>>>(ast_content, 300, W_ast_con, b_ast_con,
                                                 F[AST], 512, 64, 100000, 300, 64);
    }
    bcast_kernel<<<(50 * 128 + 255) / 256, 256, 0, stream>>>(ptest_emb, F[PT], 512, 50);
    bcast_kernel<<<(10 * 128 + 255) / 256, 256, 0, stream>>>(ftest_emb, F[FT], 512, 10);

    // -------- aggregation dispatcher --------
    auto launch_agg = [&](int i, int dout, float* outp, int ldo, int col0) {
        const int* roff = roff_all + roffoff[i];
        const int* csr  = csr_all + csroff[i];
        const int Ndst  = Nd[i];
        const bool acc  = !firstw[i];
        if (i == 5 || i == 7) {
            // pt / ft destinations: multi-block partial + finalize (sole writer)
            const int SEGS = (Ndst <= 10) ? 204 : 40;   // ~2048 blocks total
            zero_f32_kernel<<<(Ndst * dout + 255) / 256, 256, 0, stream>>>(P, Ndst * dout);
            if (dout == 128)
                agg_part_kernel<128><<<Ndst * SEGS, 256, 0, stream>>>(Wh, roff, csr, P, SEGS);
            else
                agg_part_kernel<256><<<Ndst * SEGS, 256, 0, stream>>>(Wh, roff, csr, P, SEGS);
            agg_fin_kernel<<<(Ndst * dout + 255) / 256, 256, 0, stream>>>(
                P, roff, outp, ldo, col0, Ndst, dout);
            return;
        }
        if (dout == 128) {
            int grid = (Ndst + 7) / 8;
            if (acc) agg_wave_kernel<128, true ><<<grid, 256, 0, stream>>>(Wh, roff, csr, outp, ldo, col0, Ndst);
            else     agg_wave_kernel<128, false><<<grid, 256, 0, stream>>>(Wh, roff, csr, outp, ldo, col0, Ndst);
        } else {
            int grid = (Ndst + 3) / 4;
            if (acc) agg_wave_kernel<256, true ><<<grid, 256, 0, stream>>>(Wh, roff, csr, outp, ldo, col0, Ndst);
            else     agg_wave_kernel<256, false><<<grid, 256, 0, stream>>>(Wh, roff, csr, outp, ldo, col0, Ndst);
        }
    };

    // -------- one hetero-GCN layer --------
    auto run_layer = [&](const float* Wstack, const float* bstack, int din, int dout,
                         float* const* inB, int ldin, float* const* outB, int ldout,
                         int colout) {
        for (int i = 0; i < 8; ++i) {
            const int s = stp[i], d = dtp[i];
            dim3 g((Nnt[s] + GM - 1) / GM, dout / GN);
            gemm128_kernel<<<g, 256, 0, stream>>>(
                inB[s], ldin, Wstack + (size_t)i * din * dout, bstack + (size_t)i * dout,
                Wh, dout, 0, Nnt[s], din, dout);
            launch_agg(i, dout, outB[d], ldout, colout);
        }
    };

    // L1: F[:,0:128] -> F2[:,0:128]
    run_layer(Wl[0], bl[0], 128, 128, F,  512, F2, 256, 0);
    // L2: F2[:,0:128] -> F2[:,128:256]  (concat -> F2[:,0:256])
    run_layer(Wl[1], bl[1], 128, 128, F2, 256, F2, 256, 128);
    // L3: F2[:,0:256] -> F[:,0:256]
    run_layer(Wl[2], bl[2], 256, 256, F2, 256, F,  512, 0);
    // L4: F[:,0:256] -> F[:,256:512]   (concat -> F[:,0:512])
    run_layer(Wl[3], bl[3], 256, 256, F,  512, F,  512, 256);
    // L5: F[:,0:512] -> F2[:,0:128]
    run_layer(Wl[4], bl[4], 512, 128, F,  512, F2, 256, 0);

    // -------- decoder + softmax --------
    float* out = (float*)d_out;
    decoder_kernel<<<(20000 + 255) / 256, 256, 0, stream>>>(
        F2[CFG], 256, 20000, W_dec, b_dec, out + 0, out + 40000);
    decoder_kernel<<<(100000 + 255) / 256, 256, 0, stream>>>(
        F2[AST], 256, 100000, W_dec, b_dec, out + 80000, out + 280000);
}